// Round 1
// baseline (838.429 us; speedup 1.0000x reference)
//
#include <hip/hip_runtime.h>

// ---------------------------------------------------------------------------
// GCN 2-layer (PyG GCNConv semantics) on MI355X.
// Pipeline:
//   k_init        : deg=1 (self loop), cnt=0, cursor=0
//   k_edge_deg    : deg[col]+=ew, cnt[col]+=1        (atomics)
//   k_dinv        : dinv = 1/sqrt(deg)
//   k_scan_bsum   : per-block sums of cnt
//   k_scan_bscan  : exclusive scan of block sums (1 block)
//   k_scan_write  : exclusive scan -> offset[N+1]
//   k_fill        : CSR fill: csr_row, csr_norm = dinv[r]*ew*dinv[c]
//   k_gemm        : h[N,64] = x[N,128] @ W1[128,64]  (fp32 vector, LDS-tiled)
//   k_agg1        : wave/node: acc=Σ norm*h[row] + dinv^2*h[i]; relu(acc+b1);
//                   h2[i] = Σ_c relu_c * W2[c]   (fused, out1 never stored)
//   k_agg2        : out[i] = Σ norm*h2[row] + dinv^2*h2[i] + b2
// ---------------------------------------------------------------------------

#define SCAN_T 256
#define SCAN_I 4          // 1024 elements per scan block

__global__ __launch_bounds__(256) void k_init(float* __restrict__ deg,
                                              int* __restrict__ cnt,
                                              int* __restrict__ cursor, int n) {
    int i = blockIdx.x * blockDim.x + threadIdx.x;
    if (i < n) { deg[i] = 1.0f; cnt[i] = 0; cursor[i] = 0; }
}

__global__ __launch_bounds__(256) void k_edge_deg(const int* __restrict__ ei,
                                                  const float* __restrict__ ea,
                                                  float* __restrict__ deg,
                                                  int* __restrict__ cnt, int E) {
    int e = blockIdx.x * blockDim.x + threadIdx.x;
    if (e < E) {
        int c = ei[E + e];                 // col
        atomicAdd(&deg[c], ea[e]);
        atomicAdd(&cnt[c], 1);
    }
}

__global__ __launch_bounds__(256) void k_dinv(const float* __restrict__ deg,
                                              float* __restrict__ dinv, int n) {
    int i = blockIdx.x * blockDim.x + threadIdx.x;
    if (i < n) dinv[i] = 1.0f / sqrtf(deg[i]);   // deg >= 1 always (self loop)
}

__global__ __launch_bounds__(SCAN_T) void k_scan_bsum(const int* __restrict__ cnt,
                                                      int* __restrict__ bsum, int n) {
    __shared__ int lds[SCAN_T];
    int t = threadIdx.x;
    int base = blockIdx.x * (SCAN_T * SCAN_I) + t * SCAN_I;
    int s = 0;
#pragma unroll
    for (int j = 0; j < SCAN_I; ++j) { int i = base + j; if (i < n) s += cnt[i]; }
    lds[t] = s; __syncthreads();
    for (int off = SCAN_T / 2; off > 0; off >>= 1) {
        if (t < off) lds[t] += lds[t + off];
        __syncthreads();
    }
    if (t == 0) bsum[blockIdx.x] = lds[0];
}

__global__ __launch_bounds__(SCAN_T) void k_scan_bscan(const int* __restrict__ bsum,
                                                       int* __restrict__ bscan, int nb) {
    // single block; nb <= SCAN_T
    __shared__ int lds[SCAN_T];
    int t = threadIdx.x;
    int v0 = (t < nb) ? bsum[t] : 0;
    lds[t] = v0; __syncthreads();
    for (int off = 1; off < SCAN_T; off <<= 1) {
        int v = (t >= off) ? lds[t - off] : 0;
        __syncthreads();
        lds[t] += v;
        __syncthreads();
    }
    if (t < nb) bscan[t] = lds[t] - v0;   // exclusive
}

__global__ __launch_bounds__(SCAN_T) void k_scan_write(const int* __restrict__ cnt,
                                                       const int* __restrict__ bscan,
                                                       int* __restrict__ offset,
                                                       int n, int total) {
    __shared__ int lds[SCAN_T];
    int t = threadIdx.x;
    int base = blockIdx.x * (SCAN_T * SCAN_I) + t * SCAN_I;
    int items[SCAN_I];
    int s = 0;
#pragma unroll
    for (int j = 0; j < SCAN_I; ++j) {
        int i = base + j;
        items[j] = (i < n) ? cnt[i] : 0;
        s += items[j];
    }
    lds[t] = s; __syncthreads();
    for (int off = 1; off < SCAN_T; off <<= 1) {
        int v = (t >= off) ? lds[t - off] : 0;
        __syncthreads();
        lds[t] += v;
        __syncthreads();
    }
    int run = lds[t] - s + bscan[blockIdx.x];
#pragma unroll
    for (int j = 0; j < SCAN_I; ++j) {
        int i = base + j;
        if (i < n) { offset[i] = run; run += items[j]; }
    }
    if (blockIdx.x == 0 && t == 0) offset[n] = total;
}

__global__ __launch_bounds__(256) void k_fill(const int* __restrict__ ei,
                                              const float* __restrict__ ea,
                                              const float* __restrict__ dinv,
                                              const int* __restrict__ offset,
                                              int* __restrict__ cursor,
                                              int* __restrict__ csr_row,
                                              float* __restrict__ csr_norm, int E) {
    int e = blockIdx.x * blockDim.x + threadIdx.x;
    if (e < E) {
        int r = ei[e];
        int c = ei[E + e];
        int p = offset[c] + atomicAdd(&cursor[c], 1);
        csr_row[p]  = r;
        csr_norm[p] = dinv[r] * ea[e] * dinv[c];
    }
}

// h[N,64] = x[N,128] @ W1[128,64], fp32 vector ALU.
// Block: 64 nodes x 64 channels, 256 threads, 4x4 register tile.
// LDS: xs[64][129] (pad -> conflict-free scalar reads) + ws[64][64] (k-half).
__global__ __launch_bounds__(256) void k_gemm(const float* __restrict__ x,
                                              const float* __restrict__ W1,
                                              float* __restrict__ h, int n) {
    __shared__ float xs[64][129];
    __shared__ float ws[64][64];
    int t = threadIdx.x;
    int nodeBase = blockIdx.x * 64;

    // load x tile: 64 rows x 32 float4
    for (int i = t; i < 2048; i += 256) {
        int r = i >> 5, c4 = i & 31;
        int node = nodeBase + r;
        float4 v = make_float4(0.f, 0.f, 0.f, 0.f);
        if (node < n) v = ((const float4*)x)[node * 32 + c4];
        xs[r][c4 * 4 + 0] = v.x; xs[r][c4 * 4 + 1] = v.y;
        xs[r][c4 * 4 + 2] = v.z; xs[r][c4 * 4 + 3] = v.w;
    }

    int cg = t & 15, ng = t >> 4;
    int c0 = cg * 4, n0 = ng * 4;
    float acc[4][4] = {};

    for (int half = 0; half < 2; ++half) {
        __syncthreads();   // protect ws readers from previous half / finish xs load
        // load W rows [half*64, half*64+64): 64 rows x 16 float4
        for (int i = t; i < 1024; i += 256) {
            int k = i >> 4, c4 = i & 15;
            float4 v = ((const float4*)W1)[(half * 64 + k) * 16 + c4];
            *((float4*)&ws[k][c4 * 4]) = v;
        }
        __syncthreads();
        int kbase = half * 64;
#pragma unroll 8
        for (int k = 0; k < 64; ++k) {
            float4 wv = *((const float4*)&ws[k][c0]);
            float xv[4];
#pragma unroll
            for (int j = 0; j < 4; ++j) xv[j] = xs[n0 + j][kbase + k];
#pragma unroll
            for (int j = 0; j < 4; ++j) {
                acc[j][0] += xv[j] * wv.x;
                acc[j][1] += xv[j] * wv.y;
                acc[j][2] += xv[j] * wv.z;
                acc[j][3] += xv[j] * wv.w;
            }
        }
    }

#pragma unroll
    for (int j = 0; j < 4; ++j) {
        int node = nodeBase + n0 + j;
        if (node < n) {
            float4 o = make_float4(acc[j][0], acc[j][1], acc[j][2], acc[j][3]);
            ((float4*)h)[node * 16 + cg] = o;
        }
    }
}

// One wave per node; lane = channel. Fused agg1 + bias + relu + dot(W2).
__global__ __launch_bounds__(256) void k_agg1(const float* __restrict__ h,
                                              const int* __restrict__ offset,
                                              const int* __restrict__ csr_row,
                                              const float* __restrict__ csr_norm,
                                              const float* __restrict__ dinv,
                                              const float* __restrict__ b1,
                                              const float* __restrict__ W2,
                                              float* __restrict__ h2, int n) {
    int wid  = (blockIdx.x * blockDim.x + threadIdx.x) >> 6;
    int lane = threadIdx.x & 63;
    if (wid >= n) return;
    int off0 = offset[wid], off1 = offset[wid + 1];
    float di  = dinv[wid];
    float acc = di * di * h[((long)wid << 6) + lane];   // self loop
    for (int base = off0; base < off1; base += 64) {
        int rem = off1 - base; if (rem > 64) rem = 64;
        int r = 0; float w = 0.f;
        if (lane < rem) {
            r = csr_row[base + lane];
            w = csr_norm[base + lane];
        }
        for (int j = 0; j < rem; ++j) {
            int   rj = __shfl(r, j);
            float wj = __shfl(w, j);
            acc += wj * h[((long)rj << 6) + lane];
        }
    }
    float v = fmaxf(acc + b1[lane], 0.0f);
    float p = v * W2[lane];
#pragma unroll
    for (int s = 32; s > 0; s >>= 1) p += __shfl_xor(p, s);
    if (lane == 0) h2[wid] = p;
}

// One wave per node; scalar second layer.
__global__ __launch_bounds__(256) void k_agg2(const float* __restrict__ h2,
                                              const int* __restrict__ offset,
                                              const int* __restrict__ csr_row,
                                              const float* __restrict__ csr_norm,
                                              const float* __restrict__ dinv,
                                              const float* __restrict__ b2,
                                              float* __restrict__ out, int n) {
    int wid  = (blockIdx.x * blockDim.x + threadIdx.x) >> 6;
    int lane = threadIdx.x & 63;
    if (wid >= n) return;
    int off0 = offset[wid], off1 = offset[wid + 1];
    float p = 0.f;
    for (int e = off0 + lane; e < off1; e += 64)
        p += csr_norm[e] * h2[csr_row[e]];
#pragma unroll
    for (int s = 32; s > 0; s >>= 1) p += __shfl_xor(p, s);
    if (lane == 0) {
        float di = dinv[wid];
        out[wid] = p + di * di * h2[wid] + b2[0];
    }
}

extern "C" void kernel_launch(void* const* d_in, const int* in_sizes, int n_in,
                              void* d_out, int out_size, void* d_ws, size_t ws_size,
                              hipStream_t stream) {
    const float* x  = (const float*)d_in[0];
    const int*   ei = (const int*)  d_in[1];
    const float* ea = (const float*)d_in[2];
    const float* W1 = (const float*)d_in[3];
    const float* b1 = (const float*)d_in[4];
    const float* W2 = (const float*)d_in[5];
    const float* b2 = (const float*)d_in[6];
    float* out = (float*)d_out;

    const int N = in_sizes[0] / 128;   // 100000
    const int E = in_sizes[2];         // 3200000

    // workspace carve (256B aligned)
    char* p = (char*)d_ws;
    auto alloc = [&](size_t bytes) -> void* {
        void* r = (void*)p;
        p += (bytes + 255) & ~(size_t)255;
        return r;
    };
    float* deg      = (float*)alloc((size_t)N * 4);
    float* dinv     = (float*)alloc((size_t)N * 4);
    int*   cnt      = (int*)  alloc((size_t)N * 4);
    int*   cursor   = (int*)  alloc((size_t)N * 4);
    int*   offset   = (int*)  alloc((size_t)(N + 1) * 4);
    int*   bsum     = (int*)  alloc((size_t)SCAN_T * 4);
    int*   bscan    = (int*)  alloc((size_t)SCAN_T * 4);
    int*   csr_row  = (int*)  alloc((size_t)E * 4);
    float* csr_norm = (float*)alloc((size_t)E * 4);
    float* h        = (float*)alloc((size_t)N * 64 * 4);
    float* h2       = (float*)alloc((size_t)N * 4);

    const int nb_n    = (N + 255) / 256;
    const int nb_e    = (E + 255) / 256;
    const int nb_scan = (N + SCAN_T * SCAN_I - 1) / (SCAN_T * SCAN_I);
    const int nb_gemm = (N + 63) / 64;
    const int nb_wave = (N * 64 + 255) / 256;   // one 64-wide wave per node

    k_init<<<nb_n, 256, 0, stream>>>(deg, cnt, cursor, N);
    k_edge_deg<<<nb_e, 256, 0, stream>>>(ei, ea, deg, cnt, E);
    k_dinv<<<nb_n, 256, 0, stream>>>(deg, dinv, N);
    k_scan_bsum<<<nb_scan, SCAN_T, 0, stream>>>(cnt, bsum, N);
    k_scan_bscan<<<1, SCAN_T, 0, stream>>>(bsum, bscan, nb_scan);
    k_scan_write<<<nb_scan, SCAN_T, 0, stream>>>(cnt, bscan, offset, N, E);
    k_fill<<<nb_e, 256, 0, stream>>>(ei, ea, dinv, offset, cursor, csr_row, csr_norm, E);
    k_gemm<<<nb_gemm, 256, 0, stream>>>(x, W1, h, N);
    k_agg1<<<nb_wave, 256, 0, stream>>>(h, offset, csr_row, csr_norm, dinv, b1, W2, h2, N);
    k_agg2<<<nb_wave, 256, 0, stream>>>(h2, offset, csr_row, csr_norm, dinv, b2, out, N);
}

// Round 2
// 594.868 us; speedup vs baseline: 1.4094x; 1.4094x over previous
//
#include <hip/hip_runtime.h>

// ---------------------------------------------------------------------------
// GCN 2-layer (PyG GCNConv semantics) on MI355X — R2.
// Change vs R1: 3 atomic passes -> 1.
//   k_count : rank[e] = atomicAdd(&cnt[col],1)   (the ONLY atomic pass)
//   scan    : cnt -> offset[N+1]
//   k_fill  : p = offset[col]+rank[e]; csr[p] = {row, bits(ew)}   (no atomics)
//   k_deg   : wave/node: dinv[i] = rsqrt(1 + sum ew over CSR segment)
//   k_gemm  : h = x @ W1 (fp32 vector, LDS tiled)
//   k_agg1  : wave/node, lane=channel; norm computed inline from dinv;
//             fused bias+relu+dot(W2) -> h2[N]
//   k_agg2  : wave/node scalar layer 2 -> out
// ---------------------------------------------------------------------------

#define SCAN_T 256
#define SCAN_I 4          // 1024 elements per scan block

__global__ __launch_bounds__(256) void k_zero(int* __restrict__ cnt, int n) {
    int i = blockIdx.x * blockDim.x + threadIdx.x;
    if (i < n) cnt[i] = 0;
}

// 4 edges per thread; single int atomic per edge, old value = rank.
__global__ __launch_bounds__(256) void k_count(const int* __restrict__ col,
                                               int* __restrict__ cnt,
                                               unsigned short* __restrict__ rank,
                                               int E4) {
    int t = blockIdx.x * blockDim.x + threadIdx.x;
    if (t < E4) {
        int4 c = ((const int4*)col)[t];
        ushort4 r;
        r.x = (unsigned short)atomicAdd(&cnt[c.x], 1);
        r.y = (unsigned short)atomicAdd(&cnt[c.y], 1);
        r.z = (unsigned short)atomicAdd(&cnt[c.z], 1);
        r.w = (unsigned short)atomicAdd(&cnt[c.w], 1);
        ((ushort4*)rank)[t] = r;
    }
}

__global__ __launch_bounds__(SCAN_T) void k_scan_bsum(const int* __restrict__ cnt,
                                                      int* __restrict__ bsum, int n) {
    __shared__ int lds[SCAN_T];
    int t = threadIdx.x;
    int base = blockIdx.x * (SCAN_T * SCAN_I) + t * SCAN_I;
    int s = 0;
#pragma unroll
    for (int j = 0; j < SCAN_I; ++j) { int i = base + j; if (i < n) s += cnt[i]; }
    lds[t] = s; __syncthreads();
    for (int off = SCAN_T / 2; off > 0; off >>= 1) {
        if (t < off) lds[t] += lds[t + off];
        __syncthreads();
    }
    if (t == 0) bsum[blockIdx.x] = lds[0];
}

__global__ __launch_bounds__(SCAN_T) void k_scan_bscan(const int* __restrict__ bsum,
                                                       int* __restrict__ bscan, int nb) {
    __shared__ int lds[SCAN_T];
    int t = threadIdx.x;
    int v0 = (t < nb) ? bsum[t] : 0;
    lds[t] = v0; __syncthreads();
    for (int off = 1; off < SCAN_T; off <<= 1) {
        int v = (t >= off) ? lds[t - off] : 0;
        __syncthreads();
        lds[t] += v;
        __syncthreads();
    }
    if (t < nb) bscan[t] = lds[t] - v0;   // exclusive
}

__global__ __launch_bounds__(SCAN_T) void k_scan_write(const int* __restrict__ cnt,
                                                       const int* __restrict__ bscan,
                                                       int* __restrict__ offset,
                                                       int n, int total) {
    __shared__ int lds[SCAN_T];
    int t = threadIdx.x;
    int base = blockIdx.x * (SCAN_T * SCAN_I) + t * SCAN_I;
    int items[SCAN_I];
    int s = 0;
#pragma unroll
    for (int j = 0; j < SCAN_I; ++j) {
        int i = base + j;
        items[j] = (i < n) ? cnt[i] : 0;
        s += items[j];
    }
    lds[t] = s; __syncthreads();
    for (int off = 1; off < SCAN_T; off <<= 1) {
        int v = (t >= off) ? lds[t - off] : 0;
        __syncthreads();
        lds[t] += v;
        __syncthreads();
    }
    int run = lds[t] - s + bscan[blockIdx.x];
#pragma unroll
    for (int j = 0; j < SCAN_I; ++j) {
        int i = base + j;
        if (i < n) { offset[i] = run; run += items[j]; }
    }
    if (blockIdx.x == 0 && t == 0) offset[n] = total;
}

// Atomic-free CSR fill: 4 edges/thread, one 8B scattered store per edge.
__global__ __launch_bounds__(256) void k_fill(const int* __restrict__ ei,
                                              const float* __restrict__ ea,
                                              const unsigned short* __restrict__ rank,
                                              const int* __restrict__ offset,
                                              int2* __restrict__ csr, int E, int E4) {
    int t = blockIdx.x * blockDim.x + threadIdx.x;
    if (t < E4) {
        int4    r  = ((const int4*)ei)[t];           // rows
        int4    c  = ((const int4*)(ei + E))[t];     // cols
        float4  w  = ((const float4*)ea)[t];
        ushort4 rk = ((const ushort4*)rank)[t];
        csr[offset[c.x] + rk.x] = make_int2(r.x, __float_as_int(w.x));
        csr[offset[c.y] + rk.y] = make_int2(r.y, __float_as_int(w.y));
        csr[offset[c.z] + rk.z] = make_int2(r.z, __float_as_int(w.z));
        csr[offset[c.w] + rk.w] = make_int2(r.w, __float_as_int(w.w));
    }
}

// Wave per node: deg = 1 + sum(ew over CSR segment); dinv = rsqrt(deg).
__global__ __launch_bounds__(256) void k_deg(const int2* __restrict__ csr,
                                             const int* __restrict__ offset,
                                             float* __restrict__ dinv, int n) {
    int wid  = (blockIdx.x * blockDim.x + threadIdx.x) >> 6;
    int lane = threadIdx.x & 63;
    if (wid >= n) return;
    int off0 = offset[wid], off1 = offset[wid + 1];
    float s = 0.f;
    for (int e = off0 + lane; e < off1; e += 64)
        s += __int_as_float(csr[e].y);
#pragma unroll
    for (int sh = 32; sh > 0; sh >>= 1) s += __shfl_xor(s, sh);
    if (lane == 0) dinv[wid] = rsqrtf(1.0f + s);
}

// h[N,64] = x[N,128] @ W1[128,64], fp32 vector ALU.
// Block: 64 nodes x 64 channels, 256 threads, 4x4 register tile.
__global__ __launch_bounds__(256) void k_gemm(const float* __restrict__ x,
                                              const float* __restrict__ W1,
                                              float* __restrict__ h, int n) {
    __shared__ float xs[64][129];
    __shared__ float ws[64][64];
    int t = threadIdx.x;
    int nodeBase = blockIdx.x * 64;

    for (int i = t; i < 2048; i += 256) {
        int r = i >> 5, c4 = i & 31;
        int node = nodeBase + r;
        float4 v = make_float4(0.f, 0.f, 0.f, 0.f);
        if (node < n) v = ((const float4*)x)[node * 32 + c4];
        xs[r][c4 * 4 + 0] = v.x; xs[r][c4 * 4 + 1] = v.y;
        xs[r][c4 * 4 + 2] = v.z; xs[r][c4 * 4 + 3] = v.w;
    }

    int cg = t & 15, ng = t >> 4;
    int c0 = cg * 4, n0 = ng * 4;
    float acc[4][4] = {};

    for (int half = 0; half < 2; ++half) {
        __syncthreads();
        for (int i = t; i < 1024; i += 256) {
            int k = i >> 4, c4 = i & 15;
            float4 v = ((const float4*)W1)[(half * 64 + k) * 16 + c4];
            *((float4*)&ws[k][c4 * 4]) = v;
        }
        __syncthreads();
        int kbase = half * 64;
#pragma unroll 8
        for (int k = 0; k < 64; ++k) {
            float4 wv = *((const float4*)&ws[k][c0]);
            float xv[4];
#pragma unroll
            for (int j = 0; j < 4; ++j) xv[j] = xs[n0 + j][kbase + k];
#pragma unroll
            for (int j = 0; j < 4; ++j) {
                acc[j][0] += xv[j] * wv.x;
                acc[j][1] += xv[j] * wv.y;
                acc[j][2] += xv[j] * wv.z;
                acc[j][3] += xv[j] * wv.w;
            }
        }
    }

#pragma unroll
    for (int j = 0; j < 4; ++j) {
        int node = nodeBase + n0 + j;
        if (node < n) {
            float4 o = make_float4(acc[j][0], acc[j][1], acc[j][2], acc[j][3]);
            ((float4*)h)[node * 16 + cg] = o;
        }
    }
}

// One wave per node; lane = channel. norm computed inline from dinv.
// Fused agg1 + bias + relu + dot(W2) -> h2.
__global__ __launch_bounds__(256) void k_agg1(const float* __restrict__ h,
                                              const int* __restrict__ offset,
                                              const int2* __restrict__ csr,
                                              const float* __restrict__ dinv,
                                              const float* __restrict__ b1,
                                              const float* __restrict__ W2,
                                              float* __restrict__ h2, int n) {
    int wid  = (blockIdx.x * blockDim.x + threadIdx.x) >> 6;
    int lane = threadIdx.x & 63;
    if (wid >= n) return;
    int off0 = offset[wid], off1 = offset[wid + 1];
    float di  = dinv[wid];
    float acc = di * di * h[((long)wid << 6) + lane];   // self loop
    for (int base = off0; base < off1; base += 64) {
        int rem = off1 - base; if (rem > 64) rem = 64;
        int r = 0; float w = 0.f;
        if (lane < rem) {
            int2 e = csr[base + lane];
            r = e.x;
            w = dinv[e.x] * __int_as_float(e.y) * di;
        }
        for (int j = 0; j < rem; ++j) {
            int   rj = __shfl(r, j);
            float wj = __shfl(w, j);
            acc += wj * h[((long)rj << 6) + lane];
        }
    }
    float v = fmaxf(acc + b1[lane], 0.0f);
    float p = v * W2[lane];
#pragma unroll
    for (int s = 32; s > 0; s >>= 1) p += __shfl_xor(p, s);
    if (lane == 0) h2[wid] = p;
}

// One wave per node; scalar second layer, norm inline.
__global__ __launch_bounds__(256) void k_agg2(const float* __restrict__ h2,
                                              const int* __restrict__ offset,
                                              const int2* __restrict__ csr,
                                              const float* __restrict__ dinv,
                                              const float* __restrict__ b2,
                                              float* __restrict__ out, int n) {
    int wid  = (blockIdx.x * blockDim.x + threadIdx.x) >> 6;
    int lane = threadIdx.x & 63;
    if (wid >= n) return;
    int off0 = offset[wid], off1 = offset[wid + 1];
    float di = dinv[wid];
    float p = 0.f;
    for (int e = off0 + lane; e < off1; e += 64) {
        int2 ed = csr[e];
        p += dinv[ed.x] * __int_as_float(ed.y) * h2[ed.x];
    }
    p *= di;
#pragma unroll
    for (int s = 32; s > 0; s >>= 1) p += __shfl_xor(p, s);
    if (lane == 0) out[wid] = p + di * di * h2[wid] + b2[0];
}

extern "C" void kernel_launch(void* const* d_in, const int* in_sizes, int n_in,
                              void* d_out, int out_size, void* d_ws, size_t ws_size,
                              hipStream_t stream) {
    const float* x  = (const float*)d_in[0];
    const int*   ei = (const int*)  d_in[1];
    const float* ea = (const float*)d_in[2];
    const float* W1 = (const float*)d_in[3];
    const float* b1 = (const float*)d_in[4];
    const float* W2 = (const float*)d_in[5];
    const float* b2 = (const float*)d_in[6];
    float* out = (float*)d_out;

    const int N = in_sizes[0] / 128;   // 100000
    const int E = in_sizes[2];         // 3200000
    const int E4 = E / 4;              // E is divisible by 4

    char* p = (char*)d_ws;
    auto alloc = [&](size_t bytes) -> void* {
        void* r = (void*)p;
        p += (bytes + 255) & ~(size_t)255;
        return r;
    };
    int*            cnt    = (int*)           alloc((size_t)N * 4);
    unsigned short* rank   = (unsigned short*)alloc((size_t)E * 2);
    int*            offset = (int*)           alloc((size_t)(N + 1) * 4);
    int*            bsum   = (int*)           alloc((size_t)SCAN_T * 4);
    int*            bscan  = (int*)           alloc((size_t)SCAN_T * 4);
    int2*           csr    = (int2*)          alloc((size_t)E * 8);
    float*          dinv   = (float*)         alloc((size_t)N * 4);
    float*          h      = (float*)         alloc((size_t)N * 64 * 4);
    float*          h2     = (float*)         alloc((size_t)N * 4);

    const int nb_n    = (N + 255) / 256;
    const int nb_e4   = (E4 + 255) / 256;
    const int nb_scan = (N + SCAN_T * SCAN_I - 1) / (SCAN_T * SCAN_I);
    const int nb_gemm = (N + 63) / 64;
    const int nb_wave = (N * 64 + 255) / 256;   // one 64-wide wave per node

    k_zero<<<nb_n, 256, 0, stream>>>(cnt, N);
    k_count<<<nb_e4, 256, 0, stream>>>(ei + E, cnt, rank, E4);
    k_scan_bsum<<<nb_scan, SCAN_T, 0, stream>>>(cnt, bsum, N);
    k_scan_bscan<<<1, SCAN_T, 0, stream>>>(bsum, bscan, nb_scan);
    k_scan_write<<<nb_scan, SCAN_T, 0, stream>>>(cnt, bscan, offset, N, E);
    k_fill<<<nb_e4, 256, 0, stream>>>(ei, ea, rank, offset, csr, E, E4);
    k_deg<<<nb_wave, 256, 0, stream>>>(csr, offset, dinv, N);
    k_gemm<<<nb_gemm, 256, 0, stream>>>(x, W1, h, N);
    k_agg1<<<nb_wave, 256, 0, stream>>>(h, offset, csr, dinv, b1, W2, h2, N);
    k_agg2<<<nb_wave, 256, 0, stream>>>(h2, offset, csr, dinv, b2, out, N);
}

// Round 3
// 491.483 us; speedup vs baseline: 1.7059x; 1.2104x over previous
//
#include <hip/hip_runtime.h>
#include <hip/hip_fp16.h>

// ---------------------------------------------------------------------------
// GCN 2-layer (PyG GCNConv semantics) on MI355X — R3.
// vs R2:
//  * k_count: XCD-privatized counters + workgroup-scope atomics -> executed in
//    the XCD-local L2 instead of memory-side (R1 evidence: device-scope
//    atomics ~22 G/s w/ 31 B HBM writeback each). rank = xcd<<13 | local_rank.
//  * h stored as fp16: halves the 819 MB agg1 gather traffic.
//  * k_agg1 inner loop manually unrolled 8x with batched loads: the R2 loop
//    had ~1 load in flight per wave (dynamic trip count blocked unrolling),
//    measured 4.4 TB/s effective = latency-bound. 8 in flight -> BW-bound.
// ---------------------------------------------------------------------------

#define SCAN_T 256
#define SCAN_I 4          // 1024 elements per scan block
#define NXCD 8

__device__ __forceinline__ int xcc_id() {
    int x;
    asm volatile("s_getreg_b32 %0, hwreg(HW_REG_XCC_ID, 0, 4)" : "=s"(x));
    return x & 7;
}

__global__ __launch_bounds__(256) void k_zero4(int4* __restrict__ p, int n4) {
    int i = blockIdx.x * blockDim.x + threadIdx.x;
    if (i < n4) p[i] = make_int4(0, 0, 0, 0);
}

// 4 edges/thread; one workgroup-scope (XCD-L2) atomic per edge into this
// XCD's private counter copy. Correct: copy k is only ever touched from
// XCD k's L2; end-of-kernel flush publishes to memory-side for the scan.
__global__ __launch_bounds__(256) void k_count(const int* __restrict__ col,
                                               int* __restrict__ cnt8,
                                               unsigned short* __restrict__ rank,
                                               int E4, int N) {
    int xcd = xcc_id();
    int* cnt = cnt8 + (size_t)xcd * N;
    unsigned short tag = (unsigned short)(xcd << 13);
    int t = blockIdx.x * blockDim.x + threadIdx.x;
    if (t < E4) {
        int4 c = ((const int4*)col)[t];
        ushort4 r;
        r.x = (unsigned short)__hip_atomic_fetch_add(&cnt[c.x], 1, __ATOMIC_RELAXED, __HIP_MEMORY_SCOPE_WORKGROUP) | tag;
        r.y = (unsigned short)__hip_atomic_fetch_add(&cnt[c.y], 1, __ATOMIC_RELAXED, __HIP_MEMORY_SCOPE_WORKGROUP) | tag;
        r.z = (unsigned short)__hip_atomic_fetch_add(&cnt[c.z], 1, __ATOMIC_RELAXED, __HIP_MEMORY_SCOPE_WORKGROUP) | tag;
        r.w = (unsigned short)__hip_atomic_fetch_add(&cnt[c.w], 1, __ATOMIC_RELAXED, __HIP_MEMORY_SCOPE_WORKGROUP) | tag;
        ((ushort4*)rank)[t] = r;
    }
}

__global__ __launch_bounds__(SCAN_T) void k_scan_bsum(const int* __restrict__ cnt8,
                                                      int* __restrict__ bsum, int n) {
    __shared__ int lds[SCAN_T];
    int t = threadIdx.x;
    int base = blockIdx.x * (SCAN_T * SCAN_I) + t * SCAN_I;
    int s = 0;
#pragma unroll
    for (int j = 0; j < SCAN_I; ++j) {
        int i = base + j;
        if (i < n) {
#pragma unroll
            for (int k = 0; k < NXCD; ++k) s += cnt8[(size_t)k * n + i];
        }
    }
    lds[t] = s; __syncthreads();
    for (int off = SCAN_T / 2; off > 0; off >>= 1) {
        if (t < off) lds[t] += lds[t + off];
        __syncthreads();
    }
    if (t == 0) bsum[blockIdx.x] = lds[0];
}

__global__ __launch_bounds__(SCAN_T) void k_scan_bscan(const int* __restrict__ bsum,
                                                       int* __restrict__ bscan, int nb) {
    __shared__ int lds[SCAN_T];
    int t = threadIdx.x;
    int v0 = (t < nb) ? bsum[t] : 0;
    lds[t] = v0; __syncthreads();
    for (int off = 1; off < SCAN_T; off <<= 1) {
        int v = (t >= off) ? lds[t - off] : 0;
        __syncthreads();
        lds[t] += v;
        __syncthreads();
    }
    if (t < nb) bscan[t] = lds[t] - v0;   // exclusive
}

// Exclusive scan -> offset[N+1]; also emits basek[k][i] = offset[i] +
// sum_{k'<k} cnt8[k'][i]  (per-XCD-copy base for the atomic-free fill).
__global__ __launch_bounds__(SCAN_T) void k_scan_write(const int* __restrict__ cnt8,
                                                       const int* __restrict__ bscan,
                                                       int* __restrict__ offset,
                                                       int* __restrict__ basek,
                                                       int n, int total) {
    __shared__ int lds[SCAN_T];
    int t = threadIdx.x;
    int base = blockIdx.x * (SCAN_T * SCAN_I) + t * SCAN_I;
    int items[SCAN_I];
    int s = 0;
#pragma unroll
    for (int j = 0; j < SCAN_I; ++j) {
        int i = base + j;
        int v = 0;
        if (i < n) {
#pragma unroll
            for (int k = 0; k < NXCD; ++k) v += cnt8[(size_t)k * n + i];
        }
        items[j] = v; s += v;
    }
    lds[t] = s; __syncthreads();
    for (int off = 1; off < SCAN_T; off <<= 1) {
        int v = (t >= off) ? lds[t - off] : 0;
        __syncthreads();
        lds[t] += v;
        __syncthreads();
    }
    int run = lds[t] - s + bscan[blockIdx.x];
#pragma unroll
    for (int j = 0; j < SCAN_I; ++j) {
        int i = base + j;
        if (i < n) {
            offset[i] = run;
            int b = run;
#pragma unroll
            for (int k = 0; k < NXCD; ++k) {
                basek[(size_t)k * n + i] = b;
                b += cnt8[(size_t)k * n + i];
            }
            run += items[j];
        }
    }
    if (blockIdx.x == 0 && t == 0) offset[n] = total;
}

// Atomic-free CSR fill: p = basek[xcd_of_edge][col] + local_rank.
__global__ __launch_bounds__(256) void k_fill(const int* __restrict__ ei,
                                              const float* __restrict__ ea,
                                              const unsigned short* __restrict__ rank,
                                              const int* __restrict__ basek,
                                              int2* __restrict__ csr, int E, int E4, int N) {
    int t = blockIdx.x * blockDim.x + threadIdx.x;
    if (t < E4) {
        int4    r  = ((const int4*)ei)[t];           // rows
        int4    c  = ((const int4*)(ei + E))[t];     // cols
        float4  w  = ((const float4*)ea)[t];
        ushort4 rk = ((const ushort4*)rank)[t];
        int p0 = basek[(size_t)((rk.x >> 13) & 7) * N + c.x] + (rk.x & 8191);
        int p1 = basek[(size_t)((rk.y >> 13) & 7) * N + c.y] + (rk.y & 8191);
        int p2 = basek[(size_t)((rk.z >> 13) & 7) * N + c.z] + (rk.z & 8191);
        int p3 = basek[(size_t)((rk.w >> 13) & 7) * N + c.w] + (rk.w & 8191);
        csr[p0] = make_int2(r.x, __float_as_int(w.x));
        csr[p1] = make_int2(r.y, __float_as_int(w.y));
        csr[p2] = make_int2(r.z, __float_as_int(w.z));
        csr[p3] = make_int2(r.w, __float_as_int(w.w));
    }
}

// Wave per node: deg = 1 + sum(ew over CSR segment); dinv = rsqrt(deg).
__global__ __launch_bounds__(256) void k_deg(const int2* __restrict__ csr,
                                             const int* __restrict__ offset,
                                             float* __restrict__ dinv, int n) {
    int wid  = (blockIdx.x * blockDim.x + threadIdx.x) >> 6;
    int lane = threadIdx.x & 63;
    if (wid >= n) return;
    int off0 = offset[wid], off1 = offset[wid + 1];
    float s = 0.f;
    for (int e = off0 + lane; e < off1; e += 64)
        s += __int_as_float(csr[e].y);
#pragma unroll
    for (int sh = 32; sh > 0; sh >>= 1) s += __shfl_xor(s, sh);
    if (lane == 0) dinv[wid] = rsqrtf(1.0f + s);
}

// h[N,64](fp16) = x[N,128] @ W1[128,64], fp32 vector ALU, fp16 store.
__global__ __launch_bounds__(256) void k_gemm(const float* __restrict__ x,
                                              const float* __restrict__ W1,
                                              __half* __restrict__ h, int n) {
    __shared__ float xs[64][129];
    __shared__ float ws[64][64];
    int t = threadIdx.x;
    int nodeBase = blockIdx.x * 64;

    for (int i = t; i < 2048; i += 256) {
        int r = i >> 5, c4 = i & 31;
        int node = nodeBase + r;
        float4 v = make_float4(0.f, 0.f, 0.f, 0.f);
        if (node < n) v = ((const float4*)x)[node * 32 + c4];
        xs[r][c4 * 4 + 0] = v.x; xs[r][c4 * 4 + 1] = v.y;
        xs[r][c4 * 4 + 2] = v.z; xs[r][c4 * 4 + 3] = v.w;
    }

    int cg = t & 15, ng = t >> 4;
    int c0 = cg * 4, n0 = ng * 4;
    float acc[4][4] = {};

    for (int half = 0; half < 2; ++half) {
        __syncthreads();
        for (int i = t; i < 1024; i += 256) {
            int k = i >> 4, c4 = i & 15;
            float4 v = ((const float4*)W1)[(half * 64 + k) * 16 + c4];
            *((float4*)&ws[k][c4 * 4]) = v;
        }
        __syncthreads();
        int kbase = half * 64;
#pragma unroll 8
        for (int k = 0; k < 64; ++k) {
            float4 wv = *((const float4*)&ws[k][c0]);
            float xv[4];
#pragma unroll
            for (int j = 0; j < 4; ++j) xv[j] = xs[n0 + j][kbase + k];
#pragma unroll
            for (int j = 0; j < 4; ++j) {
                acc[j][0] += xv[j] * wv.x;
                acc[j][1] += xv[j] * wv.y;
                acc[j][2] += xv[j] * wv.z;
                acc[j][3] += xv[j] * wv.w;
            }
        }
    }

#pragma unroll
    for (int j = 0; j < 4; ++j) {
        int node = nodeBase + n0 + j;
        if (node < n) {
            ushort4 o;
            o.x = __half_as_ushort(__float2half_rn(acc[j][0]));
            o.y = __half_as_ushort(__float2half_rn(acc[j][1]));
            o.z = __half_as_ushort(__float2half_rn(acc[j][2]));
            o.w = __half_as_ushort(__float2half_rn(acc[j][3]));
            ((ushort4*)h)[node * 16 + cg] = o;
        }
    }
}

// One wave per node; lane = channel. fp16 h gather, 8 loads in flight,
// 4 accumulators. Fused bias + relu + dot(W2) -> h2.
__global__ __launch_bounds__(256) void k_agg1(const __half* __restrict__ h,
                                              const int* __restrict__ offset,
                                              const int2* __restrict__ csr,
                                              const float* __restrict__ dinv,
                                              const float* __restrict__ b1,
                                              const float* __restrict__ W2,
                                              float* __restrict__ h2, int n) {
    int wid  = (blockIdx.x * blockDim.x + threadIdx.x) >> 6;
    int lane = threadIdx.x & 63;
    if (wid >= n) return;
    int off0 = offset[wid], off1 = offset[wid + 1];
    float di = dinv[wid];
    float a0 = di * di * __half2float(h[((size_t)wid << 6) + lane]);   // self loop
    float a1 = 0.f, a2 = 0.f, a3 = 0.f;

    for (int base = off0; base < off1; base += 64) {
        int rem = off1 - base; if (rem > 64) rem = 64;
        int r = 0; float w = 0.f;
        if (lane < rem) {
            int2 e = csr[base + lane];
            r = e.x;
            w = dinv[e.x] * __int_as_float(e.y) * di;
        }
        int j = 0;
        for (; j + 8 <= rem; j += 8) {
            int r0 = __shfl(r, j + 0), r1 = __shfl(r, j + 1);
            int r2 = __shfl(r, j + 2), r3 = __shfl(r, j + 3);
            int r4 = __shfl(r, j + 4), r5 = __shfl(r, j + 5);
            int r6 = __shfl(r, j + 6), r7 = __shfl(r, j + 7);
            float w0 = __shfl(w, j + 0), w1 = __shfl(w, j + 1);
            float w2 = __shfl(w, j + 2), w3 = __shfl(w, j + 3);
            float w4 = __shfl(w, j + 4), w5 = __shfl(w, j + 5);
            float w6 = __shfl(w, j + 6), w7 = __shfl(w, j + 7);
            // 8 independent gathers issued back-to-back -> 8 in flight
            float v0 = __half2float(h[((size_t)r0 << 6) + lane]);
            float v1 = __half2float(h[((size_t)r1 << 6) + lane]);
            float v2 = __half2float(h[((size_t)r2 << 6) + lane]);
            float v3 = __half2float(h[((size_t)r3 << 6) + lane]);
            float v4 = __half2float(h[((size_t)r4 << 6) + lane]);
            float v5 = __half2float(h[((size_t)r5 << 6) + lane]);
            float v6 = __half2float(h[((size_t)r6 << 6) + lane]);
            float v7 = __half2float(h[((size_t)r7 << 6) + lane]);
            a0 += w0 * v0; a1 += w1 * v1; a2 += w2 * v2; a3 += w3 * v3;
            a0 += w4 * v4; a1 += w5 * v5; a2 += w6 * v6; a3 += w7 * v7;
        }
        for (; j < rem; ++j) {
            int   rj = __shfl(r, j);
            float wj = __shfl(w, j);
            a0 += wj * __half2float(h[((size_t)rj << 6) + lane]);
        }
    }
    float acc = (a0 + a1) + (a2 + a3);
    float v = fmaxf(acc + b1[lane], 0.0f);
    float p = v * W2[lane];
#pragma unroll
    for (int s = 32; s > 0; s >>= 1) p += __shfl_xor(p, s);
    if (lane == 0) h2[wid] = p;
}

// One wave per node; scalar second layer, norm inline.
__global__ __launch_bounds__(256) void k_agg2(const float* __restrict__ h2,
                                              const int* __restrict__ offset,
                                              const int2* __restrict__ csr,
                                              const float* __restrict__ dinv,
                                              const float* __restrict__ b2,
                                              float* __restrict__ out, int n) {
    int wid  = (blockIdx.x * blockDim.x + threadIdx.x) >> 6;
    int lane = threadIdx.x & 63;
    if (wid >= n) return;
    int off0 = offset[wid], off1 = offset[wid + 1];
    float di = dinv[wid];
    float p = 0.f;
    for (int e = off0 + lane; e < off1; e += 64) {
        int2 ed = csr[e];
        p += dinv[ed.x] * __int_as_float(ed.y) * h2[ed.x];
    }
    p *= di;
#pragma unroll
    for (int s = 32; s > 0; s >>= 1) p += __shfl_xor(p, s);
    if (lane == 0) out[wid] = p + di * di * h2[wid] + b2[0];
}

extern "C" void kernel_launch(void* const* d_in, const int* in_sizes, int n_in,
                              void* d_out, int out_size, void* d_ws, size_t ws_size,
                              hipStream_t stream) {
    const float* x  = (const float*)d_in[0];
    const int*   ei = (const int*)  d_in[1];
    const float* ea = (const float*)d_in[2];
    const float* W1 = (const float*)d_in[3];
    const float* b1 = (const float*)d_in[4];
    const float* W2 = (const float*)d_in[5];
    const float* b2 = (const float*)d_in[6];
    float* out = (float*)d_out;

    const int N = in_sizes[0] / 128;   // 100000
    const int E = in_sizes[2];         // 3200000
    const int E4 = E / 4;

    char* p = (char*)d_ws;
    auto alloc = [&](size_t bytes) -> void* {
        void* r = (void*)p;
        p += (bytes + 255) & ~(size_t)255;
        return r;
    };
    int*            cnt8   = (int*)           alloc((size_t)NXCD * N * 4);
    int*            basek  = (int*)           alloc((size_t)NXCD * N * 4);
    unsigned short* rank   = (unsigned short*)alloc((size_t)E * 2);
    int*            offset = (int*)           alloc((size_t)(N + 1) * 4);
    int*            bsum   = (int*)           alloc((size_t)SCAN_T * 4);
    int*            bscan  = (int*)           alloc((size_t)SCAN_T * 4);
    int2*           csr    = (int2*)          alloc((size_t)E * 8);
    float*          dinv   = (float*)         alloc((size_t)N * 4);
    __half*         h      = (__half*)        alloc((size_t)N * 64 * 2);
    float*          h2     = (float*)         alloc((size_t)N * 4);

    const int cnt4    = (NXCD * N) / 4;          // 200000 int4s
    const int nb_z    = (cnt4 + 255) / 256;
    const int nb_e4   = (E4 + 255) / 256;
    const int nb_scan = (N + SCAN_T * SCAN_I - 1) / (SCAN_T * SCAN_I);
    const int nb_gemm = (N + 63) / 64;
    const int nb_wave = (N * 64 + 255) / 256;    // one 64-wide wave per node

    k_zero4<<<nb_z, 256, 0, stream>>>((int4*)cnt8, cnt4);
    k_count<<<nb_e4, 256, 0, stream>>>(ei + E, cnt8, rank, E4, N);
    k_scan_bsum<<<nb_scan, SCAN_T, 0, stream>>>(cnt8, bsum, N);
    k_scan_bscan<<<1, SCAN_T, 0, stream>>>(bsum, bscan, nb_scan);
    k_scan_write<<<nb_scan, SCAN_T, 0, stream>>>(cnt8, bscan, offset, basek, N, E);
    k_fill<<<nb_e4, 256, 0, stream>>>(ei, ea, rank, basek, csr, E, E4, N);
    k_deg<<<nb_wave, 256, 0, stream>>>(csr, offset, dinv, N);
    k_gemm<<<nb_gemm, 256, 0, stream>>>(x, W1, h, N);
    k_agg1<<<nb_wave, 256, 0, stream>>>(h, offset, csr, dinv, b1, W2, h2, N);
    k_agg2<<<nb_wave, 256, 0, stream>>>(h2, offset, csr, dinv, b2, out, N);
}

// Round 4
// 362.122 us; speedup vs baseline: 2.3153x; 1.3572x over previous
//
#include <hip/hip_runtime.h>
#include <hip/hip_fp16.h>

// ---------------------------------------------------------------------------
// GCN 2-layer (PyG GCNConv) on MI355X — R4.
// vs R3: CSR build rewritten as a two-level LDS counting sort. R1/R3 evidence:
// global atomics run at a fixed memory-side ~22-24 G/s regardless of scope
// (k_count 130 us, WRITE 106 MB = 33 B/atomic). New build has ZERO per-edge
// global atomics:
//   k_hist        : LDS histogram of col>>9 per 4096-edge chunk
//   k_scan_bucket : per-bucket exclusive scan over chunks (+ totals)
//   k_scan_tot    : scan bucket totals -> bucket bases
//   k_scatter     : LDS cursors; binned[pos] = {col_local<<17|row, ew}
//   k_finalize    : per-bucket (512 nodes) LDS count/ew-sum/scan ->
//                   offset[], dinv[] (absorbs k_deg), csr[] = {row, ew}
// gemm/agg1/agg2 unchanged from R3 (fp16 h, 8-deep gather pipeline).
// ---------------------------------------------------------------------------

#define BSHIFT 9
#define BSIZE 512            // nodes per bucket
#define NBUCKET 256          // max buckets (requires N <= 131072)
#define CHUNK 4096           // edges per partition chunk (1024 int4s)

// ---------------- CSR build ----------------

__global__ __launch_bounds__(256) void k_hist(const int* __restrict__ col,
                                              int* __restrict__ hist, int E4) {
    __shared__ int h[NBUCKET];
    int t = threadIdx.x, bl = blockIdx.x;
    h[t] = 0;
    __syncthreads();
#pragma unroll
    for (int i = 0; i < 4; ++i) {
        int idx = bl * 1024 + i * 256 + t;
        if (idx < E4) {
            int4 c = ((const int4*)col)[idx];
            atomicAdd(&h[c.x >> BSHIFT], 1);
            atomicAdd(&h[c.y >> BSHIFT], 1);
            atomicAdd(&h[c.z >> BSHIFT], 1);
            atomicAdd(&h[c.w >> BSHIFT], 1);
        }
    }
    __syncthreads();
    hist[bl * NBUCKET + t] = h[t];
}

// Block b: exclusive scan of hist[*][b] across chunks; emit tot[b].
__global__ __launch_bounds__(256) void k_scan_bucket(const int* __restrict__ hist,
                                                     int* __restrict__ histS,
                                                     int* __restrict__ tot, int nbl) {
    __shared__ int A[2][1024];
    int b = blockIdx.x, t = threadIdx.x;
    for (int i = t; i < 1024; i += 256) A[0][i] = (i < nbl) ? hist[i * NBUCKET + b] : 0;
    __syncthreads();
    int src = 0;
    for (int off = 1; off < 1024; off <<= 1) {
        for (int i = t; i < 1024; i += 256)
            A[1 - src][i] = A[src][i] + ((i >= off) ? A[src][i - off] : 0);
        src ^= 1;
        __syncthreads();
    }
    for (int i = t; i < nbl; i += 256)
        histS[b * nbl + i] = (i > 0) ? A[src][i - 1] : 0;
    if (t == 0) tot[b] = A[src][nbl - 1];
}

__global__ __launch_bounds__(256) void k_scan_tot(const int* __restrict__ tot,
                                                  int* __restrict__ base) {
    __shared__ int A[2][NBUCKET];
    int t = threadIdx.x;
    A[0][t] = tot[t];
    __syncthreads();
    int src = 0;
    for (int off = 1; off < NBUCKET; off <<= 1) {
        A[1 - src][t] = A[src][t] + ((t >= off) ? A[src][t - off] : 0);
        src ^= 1;
        __syncthreads();
    }
    base[t] = (t > 0) ? A[src][t - 1] : 0;
    if (t == 255) base[NBUCKET] = A[src][255];
}

// Bucket-grouped scatter; LDS cursors; one 8B store per edge, no global atomics.
__global__ __launch_bounds__(256) void k_scatter(const int* __restrict__ ei,
                                                 const float* __restrict__ ea,
                                                 const int* __restrict__ histS,
                                                 const int* __restrict__ base,
                                                 int2* __restrict__ binned,
                                                 int E, int E4, int nbl) {
    __shared__ int cur[NBUCKET];
    int t = threadIdx.x, bl = blockIdx.x;
    cur[t] = base[t] + histS[t * nbl + bl];
    __syncthreads();
#pragma unroll
    for (int i = 0; i < 4; ++i) {
        int idx = bl * 1024 + i * 256 + t;
        if (idx < E4) {
            int4   r = ((const int4*)ei)[idx];
            int4   c = ((const int4*)(ei + E))[idx];
            float4 w = ((const float4*)ea)[idx];
            int p;
            p = atomicAdd(&cur[c.x >> BSHIFT], 1);
            binned[p] = make_int2(((c.x & (BSIZE - 1)) << 17) | r.x, __float_as_int(w.x));
            p = atomicAdd(&cur[c.y >> BSHIFT], 1);
            binned[p] = make_int2(((c.y & (BSIZE - 1)) << 17) | r.y, __float_as_int(w.y));
            p = atomicAdd(&cur[c.z >> BSHIFT], 1);
            binned[p] = make_int2(((c.z & (BSIZE - 1)) << 17) | r.z, __float_as_int(w.z));
            p = atomicAdd(&cur[c.w >> BSHIFT], 1);
            binned[p] = make_int2(((c.w & (BSIZE - 1)) << 17) | r.w, __float_as_int(w.w));
        }
    }
}

// One block per bucket: count + ew-sum + scan in LDS; emit offset, dinv, csr.
__global__ __launch_bounds__(256) void k_finalize(const int2* __restrict__ binned,
                                                  const int* __restrict__ base,
                                                  int2* __restrict__ csr,
                                                  int* __restrict__ offset,
                                                  float* __restrict__ dinv,
                                                  int N, int E) {
    __shared__ int   cnt[BSIZE];
    __shared__ float fsum[BSIZE];
    __shared__ int   inc[2][BSIZE];
    __shared__ int   cur[BSIZE];
    int b = blockIdx.x, t = threadIdx.x;
    int e0 = base[b], e1 = base[b + 1];
    for (int i = t; i < BSIZE; i += 256) { cnt[i] = 0; fsum[i] = 0.f; }
    __syncthreads();
    for (int e = e0 + t; e < e1; e += 256) {
        int2 ed = binned[e];
        unsigned cl = ((unsigned)ed.x) >> 17;
        atomicAdd(&cnt[cl], 1);
        atomicAdd(&fsum[cl], __int_as_float(ed.y));
    }
    __syncthreads();
    for (int i = t; i < BSIZE; i += 256) inc[0][i] = cnt[i];
    __syncthreads();
    int src = 0;
    for (int off = 1; off < BSIZE; off <<= 1) {
        for (int i = t; i < BSIZE; i += 256)
            inc[1 - src][i] = inc[src][i] + ((i >= off) ? inc[src][i - off] : 0);
        src ^= 1;
        __syncthreads();
    }
    int nodeBase = b << BSHIFT;
    for (int i = t; i < BSIZE; i += 256) {
        int ex = (i > 0) ? inc[src][i - 1] : 0;
        cur[i] = e0 + ex;
        int node = nodeBase + i;
        if (node < N) {
            offset[node] = e0 + ex;
            dinv[node]   = rsqrtf(1.0f + fsum[i]);
        }
    }
    if (b == 0 && t == 0) offset[N] = E;
    __syncthreads();
    for (int e = e0 + t; e < e1; e += 256) {
        int2 ed = binned[e];
        unsigned cl = ((unsigned)ed.x) >> 17;
        int row = ed.x & 0x1FFFF;
        int p = atomicAdd(&cur[cl], 1);
        csr[p] = make_int2(row, ed.y);
    }
}

// ---------------- dense compute (unchanged from R3) ----------------

// h[N,64](fp16) = x[N,128] @ W1[128,64], fp32 vector ALU, fp16 store.
__global__ __launch_bounds__(256) void k_gemm(const float* __restrict__ x,
                                              const float* __restrict__ W1,
                                              __half* __restrict__ h, int n) {
    __shared__ float xs[64][129];
    __shared__ float ws[64][64];
    int t = threadIdx.x;
    int nodeBase = blockIdx.x * 64;

    for (int i = t; i < 2048; i += 256) {
        int r = i >> 5, c4 = i & 31;
        int node = nodeBase + r;
        float4 v = make_float4(0.f, 0.f, 0.f, 0.f);
        if (node < n) v = ((const float4*)x)[node * 32 + c4];
        xs[r][c4 * 4 + 0] = v.x; xs[r][c4 * 4 + 1] = v.y;
        xs[r][c4 * 4 + 2] = v.z; xs[r][c4 * 4 + 3] = v.w;
    }

    int cg = t & 15, ng = t >> 4;
    int c0 = cg * 4, n0 = ng * 4;
    float acc[4][4] = {};

    for (int half = 0; half < 2; ++half) {
        __syncthreads();
        for (int i = t; i < 1024; i += 256) {
            int k = i >> 4, c4 = i & 15;
            float4 v = ((const float4*)W1)[(half * 64 + k) * 16 + c4];
            *((float4*)&ws[k][c4 * 4]) = v;
        }
        __syncthreads();
        int kbase = half * 64;
#pragma unroll 8
        for (int k = 0; k < 64; ++k) {
            float4 wv = *((const float4*)&ws[k][c0]);
            float xv[4];
#pragma unroll
            for (int j = 0; j < 4; ++j) xv[j] = xs[n0 + j][kbase + k];
#pragma unroll
            for (int j = 0; j < 4; ++j) {
                acc[j][0] += xv[j] * wv.x;
                acc[j][1] += xv[j] * wv.y;
                acc[j][2] += xv[j] * wv.z;
                acc[j][3] += xv[j] * wv.w;
            }
        }
    }

#pragma unroll
    for (int j = 0; j < 4; ++j) {
        int node = nodeBase + n0 + j;
        if (node < n) {
            ushort4 o;
            o.x = __half_as_ushort(__float2half_rn(acc[j][0]));
            o.y = __half_as_ushort(__float2half_rn(acc[j][1]));
            o.z = __half_as_ushort(__float2half_rn(acc[j][2]));
            o.w = __half_as_ushort(__float2half_rn(acc[j][3]));
            ((ushort4*)h)[node * 16 + cg] = o;
        }
    }
}

// One wave per node; lane = channel. fp16 h gather, 8 loads in flight.
__global__ __launch_bounds__(256) void k_agg1(const __half* __restrict__ h,
                                              const int* __restrict__ offset,
                                              const int2* __restrict__ csr,
                                              const float* __restrict__ dinv,
                                              const float* __restrict__ b1,
                                              const float* __restrict__ W2,
                                              float* __restrict__ h2, int n) {
    int wid  = (blockIdx.x * blockDim.x + threadIdx.x) >> 6;
    int lane = threadIdx.x & 63;
    if (wid >= n) return;
    int off0 = offset[wid], off1 = offset[wid + 1];
    float di = dinv[wid];
    float a0 = di * di * __half2float(h[((size_t)wid << 6) + lane]);   // self loop
    float a1 = 0.f, a2 = 0.f, a3 = 0.f;

    for (int base = off0; base < off1; base += 64) {
        int rem = off1 - base; if (rem > 64) rem = 64;
        int r = 0; float w = 0.f;
        if (lane < rem) {
            int2 e = csr[base + lane];
            r = e.x;
            w = dinv[e.x] * __int_as_float(e.y) * di;
        }
        int j = 0;
        for (; j + 8 <= rem; j += 8) {
            int r0 = __shfl(r, j + 0), r1 = __shfl(r, j + 1);
            int r2 = __shfl(r, j + 2), r3 = __shfl(r, j + 3);
            int r4 = __shfl(r, j + 4), r5 = __shfl(r, j + 5);
            int r6 = __shfl(r, j + 6), r7 = __shfl(r, j + 7);
            float w0 = __shfl(w, j + 0), w1 = __shfl(w, j + 1);
            float w2 = __shfl(w, j + 2), w3 = __shfl(w, j + 3);
            float w4 = __shfl(w, j + 4), w5 = __shfl(w, j + 5);
            float w6 = __shfl(w, j + 6), w7 = __shfl(w, j + 7);
            float v0 = __half2float(h[((size_t)r0 << 6) + lane]);
            float v1 = __half2float(h[((size_t)r1 << 6) + lane]);
            float v2 = __half2float(h[((size_t)r2 << 6) + lane]);
            float v3 = __half2float(h[((size_t)r3 << 6) + lane]);
            float v4 = __half2float(h[((size_t)r4 << 6) + lane]);
            float v5 = __half2float(h[((size_t)r5 << 6) + lane]);
            float v6 = __half2float(h[((size_t)r6 << 6) + lane]);
            float v7 = __half2float(h[((size_t)r7 << 6) + lane]);
            a0 += w0 * v0; a1 += w1 * v1; a2 += w2 * v2; a3 += w3 * v3;
            a0 += w4 * v4; a1 += w5 * v5; a2 += w6 * v6; a3 += w7 * v7;
        }
        for (; j < rem; ++j) {
            int   rj = __shfl(r, j);
            float wj = __shfl(w, j);
            a0 += wj * __half2float(h[((size_t)rj << 6) + lane]);
        }
    }
    float acc = (a0 + a1) + (a2 + a3);
    float v = fmaxf(acc + b1[lane], 0.0f);
    float p = v * W2[lane];
#pragma unroll
    for (int s = 32; s > 0; s >>= 1) p += __shfl_xor(p, s);
    if (lane == 0) h2[wid] = p;
}

// One wave per node; scalar second layer, norm inline.
__global__ __launch_bounds__(256) void k_agg2(const float* __restrict__ h2,
                                              const int* __restrict__ offset,
                                              const int2* __restrict__ csr,
                                              const float* __restrict__ dinv,
                                              const float* __restrict__ b2,
                                              float* __restrict__ out, int n) {
    int wid  = (blockIdx.x * blockDim.x + threadIdx.x) >> 6;
    int lane = threadIdx.x & 63;
    if (wid >= n) return;
    int off0 = offset[wid], off1 = offset[wid + 1];
    float di = dinv[wid];
    float p = 0.f;
    for (int e = off0 + lane; e < off1; e += 64) {
        int2 ed = csr[e];
        p += dinv[ed.x] * __int_as_float(ed.y) * h2[ed.x];
    }
    p *= di;
#pragma unroll
    for (int s = 32; s > 0; s >>= 1) p += __shfl_xor(p, s);
    if (lane == 0) out[wid] = p + di * di * h2[wid] + b2[0];
}

extern "C" void kernel_launch(void* const* d_in, const int* in_sizes, int n_in,
                              void* d_out, int out_size, void* d_ws, size_t ws_size,
                              hipStream_t stream) {
    const float* x  = (const float*)d_in[0];
    const int*   ei = (const int*)  d_in[1];
    const float* ea = (const float*)d_in[2];
    const float* W1 = (const float*)d_in[3];
    const float* b1 = (const float*)d_in[4];
    const float* W2 = (const float*)d_in[5];
    const float* b2 = (const float*)d_in[6];
    float* out = (float*)d_out;

    const int N  = in_sizes[0] / 128;   // 100000 (must be <= 131072)
    const int E  = in_sizes[2];         // 3200000
    const int E4 = E / 4;
    const int nbl  = (E4 + 1023) / 1024;        // partition chunks (<=1024)
    const int nbkt = (N + BSIZE - 1) / BSIZE;   // active buckets (196)

    char* p = (char*)d_ws;
    auto alloc = [&](size_t bytes) -> void* {
        void* r = (void*)p;
        p += (bytes + 255) & ~(size_t)255;
        return r;
    };
    int*    hist   = (int*)   alloc((size_t)nbl * NBUCKET * 4);
    int*    histS  = (int*)   alloc((size_t)NBUCKET * nbl * 4);
    int*    tot    = (int*)   alloc((size_t)NBUCKET * 4);
    int*    base   = (int*)   alloc((size_t)(NBUCKET + 1) * 4);
    int2*   binned = (int2*)  alloc((size_t)E * 8);
    int2*   csr    = (int2*)  alloc((size_t)E * 8);
    int*    offset = (int*)   alloc((size_t)(N + 1) * 4);
    float*  dinv   = (float*) alloc((size_t)N * 4);
    __half* h      = (__half*)alloc((size_t)N * 64 * 2);
    float*  h2     = (float*) alloc((size_t)N * 4);

    const int nb_gemm = (N + 63) / 64;
    const int nb_wave = (N * 64 + 255) / 256;   // one 64-wide wave per node

    k_hist<<<nbl, 256, 0, stream>>>(ei + E, hist, E4);
    k_scan_bucket<<<NBUCKET, 256, 0, stream>>>(hist, histS, tot, nbl);
    k_scan_tot<<<1, 256, 0, stream>>>(tot, base);
    k_scatter<<<nbl, 256, 0, stream>>>(ei, ea, histS, base, binned, E, E4, nbl);
    k_finalize<<<nbkt, 256, 0, stream>>>(binned, base, csr, offset, dinv, N, E);
    k_gemm<<<nb_gemm, 256, 0, stream>>>(x, W1, h, N);
    k_agg1<<<nb_wave, 256, 0, stream>>>(h, offset, csr, dinv, b1, W2, h2, N);
    k_agg2<<<nb_wave, 256, 0, stream>>>(h2, offset, csr, dinv, b2, out, N);
}

// Round 5
// 345.278 us; speedup vs baseline: 2.4283x; 1.0488x over previous
//
#include <hip/hip_runtime.h>
#include <hip/hip_fp16.h>

// ---------------------------------------------------------------------------
// GCN 2-layer (PyG GCNConv) on MI355X — R5.
// vs R4 (agg1 was 90 us: VALUBusy 50%, LDS-pipe bound on 2 bpermutes/edge):
//  * agg1/agg2: wave-uniform CSR segment read via readfirstlane-forced
//    scalar loads (s_load, SMEM pipe) — zero shuffles, zero per-edge VALU
//    addressing (gather = global_load_ushort with SGPR base).
//  * dinv folded into h: gemm writes hs = dinv*(x@W1) fp16; agg1 needs only
//    ew per edge (no dinv[row] random gather); agg1 writes h2s = dinv*h2;
//    agg2 gathers only h2s. All per-edge dinv gathers eliminated.
// CSR build (LDS counting sort, zero global atomics) unchanged from R4.
// ---------------------------------------------------------------------------

#define BSHIFT 9
#define BSIZE 512            // nodes per bucket
#define NBUCKET 256          // max buckets (requires N <= 131072)

// ---------------- CSR build ----------------

__global__ __launch_bounds__(256) void k_hist(const int* __restrict__ col,
                                              int* __restrict__ hist, int E4) {
    __shared__ int h[NBUCKET];
    int t = threadIdx.x, bl = blockIdx.x;
    h[t] = 0;
    __syncthreads();
#pragma unroll
    for (int i = 0; i < 4; ++i) {
        int idx = bl * 1024 + i * 256 + t;
        if (idx < E4) {
            int4 c = ((const int4*)col)[idx];
            atomicAdd(&h[c.x >> BSHIFT], 1);
            atomicAdd(&h[c.y >> BSHIFT], 1);
            atomicAdd(&h[c.z >> BSHIFT], 1);
            atomicAdd(&h[c.w >> BSHIFT], 1);
        }
    }
    __syncthreads();
    hist[bl * NBUCKET + t] = h[t];
}

// Block b: exclusive scan of hist[*][b] across chunks; emit tot[b].
__global__ __launch_bounds__(256) void k_scan_bucket(const int* __restrict__ hist,
                                                     int* __restrict__ histS,
                                                     int* __restrict__ tot, int nbl) {
    __shared__ int A[2][1024];
    int b = blockIdx.x, t = threadIdx.x;
    for (int i = t; i < 1024; i += 256) A[0][i] = (i < nbl) ? hist[i * NBUCKET + b] : 0;
    __syncthreads();
    int src = 0;
    for (int off = 1; off < 1024; off <<= 1) {
        for (int i = t; i < 1024; i += 256)
            A[1 - src][i] = A[src][i] + ((i >= off) ? A[src][i - off] : 0);
        src ^= 1;
        __syncthreads();
    }
    for (int i = t; i < nbl; i += 256)
        histS[b * nbl + i] = (i > 0) ? A[src][i - 1] : 0;
    if (t == 0) tot[b] = A[src][nbl - 1];
}

__global__ __launch_bounds__(256) void k_scan_tot(const int* __restrict__ tot,
                                                  int* __restrict__ base) {
    __shared__ int A[2][NBUCKET];
    int t = threadIdx.x;
    A[0][t] = tot[t];
    __syncthreads();
    int src = 0;
    for (int off = 1; off < NBUCKET; off <<= 1) {
        A[1 - src][t] = A[src][t] + ((t >= off) ? A[src][t - off] : 0);
        src ^= 1;
        __syncthreads();
    }
    base[t] = (t > 0) ? A[src][t - 1] : 0;
    if (t == 255) base[NBUCKET] = A[src][255];
}

// Bucket-grouped scatter; LDS cursors; one 8B store per edge, no global atomics.
__global__ __launch_bounds__(256) void k_scatter(const int* __restrict__ ei,
                                                 const float* __restrict__ ea,
                                                 const int* __restrict__ histS,
                                                 const int* __restrict__ base,
                                                 int2* __restrict__ binned,
                                                 int E, int E4, int nbl) {
    __shared__ int cur[NBUCKET];
    int t = threadIdx.x, bl = blockIdx.x;
    cur[t] = base[t] + histS[t * nbl + bl];
    __syncthreads();
#pragma unroll
    for (int i = 0; i < 4; ++i) {
        int idx = bl * 1024 + i * 256 + t;
        if (idx < E4) {
            int4   r = ((const int4*)ei)[idx];
            int4   c = ((const int4*)(ei + E))[idx];
            float4 w = ((const float4*)ea)[idx];
            int p;
            p = atomicAdd(&cur[c.x >> BSHIFT], 1);
            binned[p] = make_int2(((c.x & (BSIZE - 1)) << 17) | r.x, __float_as_int(w.x));
            p = atomicAdd(&cur[c.y >> BSHIFT], 1);
            binned[p] = make_int2(((c.y & (BSIZE - 1)) << 17) | r.y, __float_as_int(w.y));
            p = atomicAdd(&cur[c.z >> BSHIFT], 1);
            binned[p] = make_int2(((c.z & (BSIZE - 1)) << 17) | r.z, __float_as_int(w.z));
            p = atomicAdd(&cur[c.w >> BSHIFT], 1);
            binned[p] = make_int2(((c.w & (BSIZE - 1)) << 17) | r.w, __float_as_int(w.w));
        }
    }
}

// One block per bucket: count + ew-sum + scan in LDS; emit offset, dinv, csr.
__global__ __launch_bounds__(256) void k_finalize(const int2* __restrict__ binned,
                                                  const int* __restrict__ base,
                                                  int2* __restrict__ csr,
                                                  int* __restrict__ offset,
                                                  float* __restrict__ dinv,
                                                  int N, int E) {
    __shared__ int   cnt[BSIZE];
    __shared__ float fsum[BSIZE];
    __shared__ int   inc[2][BSIZE];
    __shared__ int   cur[BSIZE];
    int b = blockIdx.x, t = threadIdx.x;
    int e0 = base[b], e1 = base[b + 1];
    for (int i = t; i < BSIZE; i += 256) { cnt[i] = 0; fsum[i] = 0.f; }
    __syncthreads();
    for (int e = e0 + t; e < e1; e += 256) {
        int2 ed = binned[e];
        unsigned cl = ((unsigned)ed.x) >> 17;
        atomicAdd(&cnt[cl], 1);
        atomicAdd(&fsum[cl], __int_as_float(ed.y));
    }
    __syncthreads();
    for (int i = t; i < BSIZE; i += 256) inc[0][i] = cnt[i];
    __syncthreads();
    int src = 0;
    for (int off = 1; off < BSIZE; off <<= 1) {
        for (int i = t; i < BSIZE; i += 256)
            inc[1 - src][i] = inc[src][i] + ((i >= off) ? inc[src][i - off] : 0);
        src ^= 1;
        __syncthreads();
    }
    int nodeBase = b << BSHIFT;
    for (int i = t; i < BSIZE; i += 256) {
        int ex = (i > 0) ? inc[src][i - 1] : 0;
        cur[i] = e0 + ex;
        int node = nodeBase + i;
        if (node < N) {
            offset[node] = e0 + ex;
            dinv[node]   = rsqrtf(1.0f + fsum[i]);
        }
    }
    if (b == 0 && t == 0) offset[N] = E;
    __syncthreads();
    for (int e = e0 + t; e < e1; e += 256) {
        int2 ed = binned[e];
        unsigned cl = ((unsigned)ed.x) >> 17;
        int row = ed.x & 0x1FFFF;
        int p = atomicAdd(&cur[cl], 1);
        csr[p] = make_int2(row, ed.y);
    }
}

// ---------------- dense compute ----------------

// hs[N,64](fp16) = dinv[node] * (x[N,128] @ W1[128,64]); fp32 vector ALU.
__global__ __launch_bounds__(256) void k_gemm(const float* __restrict__ x,
                                              const float* __restrict__ W1,
                                              const float* __restrict__ dinv,
                                              __half* __restrict__ hs, int n) {
    __shared__ float xs[64][129];
    __shared__ float ws[64][64];
    int t = threadIdx.x;
    int nodeBase = blockIdx.x * 64;

    for (int i = t; i < 2048; i += 256) {
        int r = i >> 5, c4 = i & 31;
        int node = nodeBase + r;
        float4 v = make_float4(0.f, 0.f, 0.f, 0.f);
        if (node < n) v = ((const float4*)x)[node * 32 + c4];
        xs[r][c4 * 4 + 0] = v.x; xs[r][c4 * 4 + 1] = v.y;
        xs[r][c4 * 4 + 2] = v.z; xs[r][c4 * 4 + 3] = v.w;
    }

    int cg = t & 15, ng = t >> 4;
    int c0 = cg * 4, n0 = ng * 4;
    float acc[4][4] = {};

    for (int half = 0; half < 2; ++half) {
        __syncthreads();
        for (int i = t; i < 1024; i += 256) {
            int k = i >> 4, c4 = i & 15;
            float4 v = ((const float4*)W1)[(half * 64 + k) * 16 + c4];
            *((float4*)&ws[k][c4 * 4]) = v;
        }
        __syncthreads();
        int kbase = half * 64;
#pragma unroll 8
        for (int k = 0; k < 64; ++k) {
            float4 wv = *((const float4*)&ws[k][c0]);
            float xv[4];
#pragma unroll
            for (int j = 0; j < 4; ++j) xv[j] = xs[n0 + j][kbase + k];
#pragma unroll
            for (int j = 0; j < 4; ++j) {
                acc[j][0] += xv[j] * wv.x;
                acc[j][1] += xv[j] * wv.y;
                acc[j][2] += xv[j] * wv.z;
                acc[j][3] += xv[j] * wv.w;
            }
        }
    }

#pragma unroll
    for (int j = 0; j < 4; ++j) {
        int node = nodeBase + n0 + j;
        if (node < n) {
            float s = dinv[node];
            ushort4 o;
            o.x = __half_as_ushort(__float2half_rn(acc[j][0] * s));
            o.y = __half_as_ushort(__float2half_rn(acc[j][1] * s));
            o.z = __half_as_ushort(__float2half_rn(acc[j][2] * s));
            o.w = __half_as_ushort(__float2half_rn(acc[j][3] * s));
            ((ushort4*)hs)[node * 16 + cg] = o;
        }
    }
}

// One wave per node; lane = channel. Wave-uniform scalar CSR reads (s_load),
// zero shuffles; per-edge work = 1 gather + cvt + fma.
// S[c] = hs[i][c] + sum_j ew_j * hs[r_j][c];  v = relu(di*S + b1);
// h2s[i] = di * dot(v, W2).
__global__ __launch_bounds__(256) void k_agg1(const __half* __restrict__ hs,
                                              const int* __restrict__ offset,
                                              const int2* __restrict__ csr,
                                              const float* __restrict__ dinv,
                                              const float* __restrict__ b1,
                                              const float* __restrict__ W2,
                                              float* __restrict__ h2s, int n) {
    int wid = __builtin_amdgcn_readfirstlane((int)((blockIdx.x * blockDim.x + threadIdx.x) >> 6));
    int lane = threadIdx.x & 63;
    if (wid >= n) return;
    int off0 = __builtin_amdgcn_readfirstlane(offset[wid]);
    int off1 = __builtin_amdgcn_readfirstlane(offset[wid + 1]);
    float di = dinv[wid];
    float a0 = __half2float(hs[((size_t)wid << 6) + lane]);   // self term hs[i]
    float a1 = 0.f, a2 = 0.f, a3 = 0.f;

    int j = off0;
    for (; j + 8 <= off1; j += 8) {
        int2 e0 = csr[j + 0], e1 = csr[j + 1], e2 = csr[j + 2], e3 = csr[j + 3];
        int2 e4 = csr[j + 4], e5 = csr[j + 5], e6 = csr[j + 6], e7 = csr[j + 7];
        float v0 = __half2float(hs[((size_t)e0.x << 6) + lane]);
        float v1 = __half2float(hs[((size_t)e1.x << 6) + lane]);
        float v2 = __half2float(hs[((size_t)e2.x << 6) + lane]);
        float v3 = __half2float(hs[((size_t)e3.x << 6) + lane]);
        float v4 = __half2float(hs[((size_t)e4.x << 6) + lane]);
        float v5 = __half2float(hs[((size_t)e5.x << 6) + lane]);
        float v6 = __half2float(hs[((size_t)e6.x << 6) + lane]);
        float v7 = __half2float(hs[((size_t)e7.x << 6) + lane]);
        a0 += __int_as_float(e0.y) * v0; a1 += __int_as_float(e1.y) * v1;
        a2 += __int_as_float(e2.y) * v2; a3 += __int_as_float(e3.y) * v3;
        a0 += __int_as_float(e4.y) * v4; a1 += __int_as_float(e5.y) * v5;
        a2 += __int_as_float(e6.y) * v6; a3 += __int_as_float(e7.y) * v7;
    }
    for (; j < off1; ++j) {
        int2 e = csr[j];
        a0 += __int_as_float(e.y) * __half2float(hs[((size_t)e.x << 6) + lane]);
    }
    float S = (a0 + a1) + (a2 + a3);
    float v = fmaxf(di * S + b1[lane], 0.0f);
    float p = v * W2[lane];
#pragma unroll
    for (int s = 32; s > 0; s >>= 1) p += __shfl_xor(p, s);
    if (lane == 0) h2s[wid] = di * p;
}

// One wave per node; out[i] = di*(sum_j ew_j*h2s[r_j] + h2s[i]) + b2.
__global__ __launch_bounds__(256) void k_agg2(const float* __restrict__ h2s,
                                              const int* __restrict__ offset,
                                              const int2* __restrict__ csr,
                                              const float* __restrict__ dinv,
                                              const float* __restrict__ b2,
                                              float* __restrict__ out, int n) {
    int wid = __builtin_amdgcn_readfirstlane((int)((blockIdx.x * blockDim.x + threadIdx.x) >> 6));
    int lane = threadIdx.x & 63;
    if (wid >= n) return;
    int off0 = __builtin_amdgcn_readfirstlane(offset[wid]);
    int off1 = __builtin_amdgcn_readfirstlane(offset[wid + 1]);
    float di = dinv[wid];
    float p = 0.f;
    for (int e = off0 + lane; e < off1; e += 64) {
        int2 ed = csr[e];
        p += __int_as_float(ed.y) * h2s[ed.x];
    }
#pragma unroll
    for (int s = 32; s > 0; s >>= 1) p += __shfl_xor(p, s);
    if (lane == 0) out[wid] = di * (p + h2s[wid]) + b2[0];
}

extern "C" void kernel_launch(void* const* d_in, const int* in_sizes, int n_in,
                              void* d_out, int out_size, void* d_ws, size_t ws_size,
                              hipStream_t stream) {
    const float* x  = (const float*)d_in[0];
    const int*   ei = (const int*)  d_in[1];
    const float* ea = (const float*)d_in[2];
    const float* W1 = (const float*)d_in[3];
    const float* b1 = (const float*)d_in[4];
    const float* W2 = (const float*)d_in[5];
    const float* b2 = (const float*)d_in[6];
    float* out = (float*)d_out;

    const int N  = in_sizes[0] / 128;   // 100000 (must be <= 131072)
    const int E  = in_sizes[2];         // 3200000
    const int E4 = E / 4;
    const int nbl  = (E4 + 1023) / 1024;        // partition chunks (<=1024)
    const int nbkt = (N + BSIZE - 1) / BSIZE;   // active buckets (196)

    char* p = (char*)d_ws;
    auto alloc = [&](size_t bytes) -> void* {
        void* r = (void*)p;
        p += (bytes + 255) & ~(size_t)255;
        return r;
    };
    int*    hist   = (int*)   alloc((size_t)nbl * NBUCKET * 4);
    int*    histS  = (int*)   alloc((size_t)NBUCKET * nbl * 4);
    int*    tot    = (int*)   alloc((size_t)NBUCKET * 4);
    int*    base   = (int*)   alloc((size_t)(NBUCKET + 1) * 4);
    int2*   binned = (int2*)  alloc((size_t)E * 8);
    int2*   csr    = (int2*)  alloc((size_t)E * 8);
    int*    offset = (int*)   alloc((size_t)(N + 1) * 4);
    float*  dinv   = (float*) alloc((size_t)N * 4);
    __half* hs     = (__half*)alloc((size_t)N * 64 * 2);
    float*  h2s    = (float*) alloc((size_t)N * 4);

    const int nb_gemm = (N + 63) / 64;
    const int nb_wave = (N * 64 + 255) / 256;   // one 64-wide wave per node

    k_hist<<<nbl, 256, 0, stream>>>(ei + E, hist, E4);
    k_scan_bucket<<<NBUCKET, 256, 0, stream>>>(hist, histS, tot, nbl);
    k_scan_tot<<<1, 256, 0, stream>>>(tot, base);
    k_scatter<<<nbl, 256, 0, stream>>>(ei, ea, histS, base, binned, E, E4, nbl);
    k_finalize<<<nbkt, 256, 0, stream>>>(binned, base, csr, offset, dinv, N, E);
    k_gemm<<<nb_gemm, 256, 0, stream>>>(x, W1, dinv, hs, N);
    k_agg1<<<nb_wave, 256, 0, stream>>>(hs, offset, csr, dinv, b1, W2, h2s, N);
    k_agg2<<<nb_wave, 256, 0, stream>>>(h2s, offset, csr, dinv, b2, out, N);
}

// Round 6
// 323.701 us; speedup vs baseline: 2.5901x; 1.0667x over previous
//
#include <hip/hip_runtime.h>
#include <hip/hip_fp16.h>

// ---------------------------------------------------------------------------
// GCN 2-layer (PyG GCNConv) on MI355X — R6.
// vs R5 (agg1 77 us, 2.38 TB/s, VALU 26%, no pipe saturated -> bound by
// vmem-instruction slots: 1 line per gather instruction):
//  * k_agg1: transposed batched gather. Wave = 8 groups x 8 subs; per
//    instruction lane (g,s) loads 16 B (8 fp16 ch) of edge j+g ->
//    one global_load_dwordx4 = 8 edges = 8 cache lines per queue slot.
//    Per-channel sums reduced across groups once per node (shfl_xor 8/16/32).
// CSR build (LDS counting sort), gemm (hs = dinv*(x@W1) fp16), agg2 unchanged.
// ---------------------------------------------------------------------------

#define BSHIFT 9
#define BSIZE 512            // nodes per bucket
#define NBUCKET 256          // max buckets (requires N <= 131072)

// ---------------- CSR build ----------------

__global__ __launch_bounds__(256) void k_hist(const int* __restrict__ col,
                                              int* __restrict__ hist, int E4) {
    __shared__ int h[NBUCKET];
    int t = threadIdx.x, bl = blockIdx.x;
    h[t] = 0;
    __syncthreads();
#pragma unroll
    for (int i = 0; i < 4; ++i) {
        int idx = bl * 1024 + i * 256 + t;
        if (idx < E4) {
            int4 c = ((const int4*)col)[idx];
            atomicAdd(&h[c.x >> BSHIFT], 1);
            atomicAdd(&h[c.y >> BSHIFT], 1);
            atomicAdd(&h[c.z >> BSHIFT], 1);
            atomicAdd(&h[c.w >> BSHIFT], 1);
        }
    }
    __syncthreads();
    hist[bl * NBUCKET + t] = h[t];
}

// Block b: exclusive scan of hist[*][b] across chunks; emit tot[b].
__global__ __launch_bounds__(256) void k_scan_bucket(const int* __restrict__ hist,
                                                     int* __restrict__ histS,
                                                     int* __restrict__ tot, int nbl) {
    __shared__ int A[2][1024];
    int b = blockIdx.x, t = threadIdx.x;
    for (int i = t; i < 1024; i += 256) A[0][i] = (i < nbl) ? hist[i * NBUCKET + b] : 0;
    __syncthreads();
    int src = 0;
    for (int off = 1; off < 1024; off <<= 1) {
        for (int i = t; i < 1024; i += 256)
            A[1 - src][i] = A[src][i] + ((i >= off) ? A[src][i - off] : 0);
        src ^= 1;
        __syncthreads();
    }
    for (int i = t; i < nbl; i += 256)
        histS[b * nbl + i] = (i > 0) ? A[src][i - 1] : 0;
    if (t == 0) tot[b] = A[src][nbl - 1];
}

__global__ __launch_bounds__(256) void k_scan_tot(const int* __restrict__ tot,
                                                  int* __restrict__ base) {
    __shared__ int A[2][NBUCKET];
    int t = threadIdx.x;
    A[0][t] = tot[t];
    __syncthreads();
    int src = 0;
    for (int off = 1; off < NBUCKET; off <<= 1) {
        A[1 - src][t] = A[src][t] + ((t >= off) ? A[src][t - off] : 0);
        src ^= 1;
        __syncthreads();
    }
    base[t] = (t > 0) ? A[src][t - 1] : 0;
    if (t == 255) base[NBUCKET] = A[src][255];
}

// Bucket-grouped scatter; LDS cursors; one 8B store per edge, no global atomics.
__global__ __launch_bounds__(256) void k_scatter(const int* __restrict__ ei,
                                                 const float* __restrict__ ea,
                                                 const int* __restrict__ histS,
                                                 const int* __restrict__ base,
                                                 int2* __restrict__ binned,
                                                 int E, int E4, int nbl) {
    __shared__ int cur[NBUCKET];
    int t = threadIdx.x, bl = blockIdx.x;
    cur[t] = base[t] + histS[t * nbl + bl];
    __syncthreads();
#pragma unroll
    for (int i = 0; i < 4; ++i) {
        int idx = bl * 1024 + i * 256 + t;
        if (idx < E4) {
            int4   r = ((const int4*)ei)[idx];
            int4   c = ((const int4*)(ei + E))[idx];
            float4 w = ((const float4*)ea)[idx];
            int p;
            p = atomicAdd(&cur[c.x >> BSHIFT], 1);
            binned[p] = make_int2(((c.x & (BSIZE - 1)) << 17) | r.x, __float_as_int(w.x));
            p = atomicAdd(&cur[c.y >> BSHIFT], 1);
            binned[p] = make_int2(((c.y & (BSIZE - 1)) << 17) | r.y, __float_as_int(w.y));
            p = atomicAdd(&cur[c.z >> BSHIFT], 1);
            binned[p] = make_int2(((c.z & (BSIZE - 1)) << 17) | r.z, __float_as_int(w.z));
            p = atomicAdd(&cur[c.w >> BSHIFT], 1);
            binned[p] = make_int2(((c.w & (BSIZE - 1)) << 17) | r.w, __float_as_int(w.w));
        }
    }
}

// One block per bucket: count + ew-sum + scan in LDS; emit offset, dinv, csr.
__global__ __launch_bounds__(256) void k_finalize(const int2* __restrict__ binned,
                                                  const int* __restrict__ base,
                                                  int2* __restrict__ csr,
                                                  int* __restrict__ offset,
                                                  float* __restrict__ dinv,
                                                  int N, int E) {
    __shared__ int   cnt[BSIZE];
    __shared__ float fsum[BSIZE];
    __shared__ int   inc[2][BSIZE];
    __shared__ int   cur[BSIZE];
    int b = blockIdx.x, t = threadIdx.x;
    int e0 = base[b], e1 = base[b + 1];
    for (int i = t; i < BSIZE; i += 256) { cnt[i] = 0; fsum[i] = 0.f; }
    __syncthreads();
    for (int e = e0 + t; e < e1; e += 256) {
        int2 ed = binned[e];
        unsigned cl = ((unsigned)ed.x) >> 17;
        atomicAdd(&cnt[cl], 1);
        atomicAdd(&fsum[cl], __int_as_float(ed.y));
    }
    __syncthreads();
    for (int i = t; i < BSIZE; i += 256) inc[0][i] = cnt[i];
    __syncthreads();
    int src = 0;
    for (int off = 1; off < BSIZE; off <<= 1) {
        for (int i = t; i < BSIZE; i += 256)
            inc[1 - src][i] = inc[src][i] + ((i >= off) ? inc[src][i - off] : 0);
        src ^= 1;
        __syncthreads();
    }
    int nodeBase = b << BSHIFT;
    for (int i = t; i < BSIZE; i += 256) {
        int ex = (i > 0) ? inc[src][i - 1] : 0;
        cur[i] = e0 + ex;
        int node = nodeBase + i;
        if (node < N) {
            offset[node] = e0 + ex;
            dinv[node]   = rsqrtf(1.0f + fsum[i]);
        }
    }
    if (b == 0 && t == 0) offset[N] = E;
    __syncthreads();
    for (int e = e0 + t; e < e1; e += 256) {
        int2 ed = binned[e];
        unsigned cl = ((unsigned)ed.x) >> 17;
        int row = ed.x & 0x1FFFF;
        int p = atomicAdd(&cur[cl], 1);
        csr[p] = make_int2(row, ed.y);
    }
}

// ---------------- dense compute ----------------

// hs[N,64](fp16) = dinv[node] * (x[N,128] @ W1[128,64]); fp32 vector ALU.
__global__ __launch_bounds__(256) void k_gemm(const float* __restrict__ x,
                                              const float* __restrict__ W1,
                                              const float* __restrict__ dinv,
                                              __half* __restrict__ hs, int n) {
    __shared__ float xs[64][129];
    __shared__ float ws[64][64];
    int t = threadIdx.x;
    int nodeBase = blockIdx.x * 64;

    for (int i = t; i < 2048; i += 256) {
        int r = i >> 5, c4 = i & 31;
        int node = nodeBase + r;
        float4 v = make_float4(0.f, 0.f, 0.f, 0.f);
        if (node < n) v = ((const float4*)x)[node * 32 + c4];
        xs[r][c4 * 4 + 0] = v.x; xs[r][c4 * 4 + 1] = v.y;
        xs[r][c4 * 4 + 2] = v.z; xs[r][c4 * 4 + 3] = v.w;
    }

    int cg = t & 15, ng = t >> 4;
    int c0 = cg * 4, n0 = ng * 4;
    float acc[4][4] = {};

    for (int half = 0; half < 2; ++half) {
        __syncthreads();
        for (int i = t; i < 1024; i += 256) {
            int k = i >> 4, c4 = i & 15;
            float4 v = ((const float4*)W1)[(half * 64 + k) * 16 + c4];
            *((float4*)&ws[k][c4 * 4]) = v;
        }
        __syncthreads();
        int kbase = half * 64;
#pragma unroll 8
        for (int k = 0; k < 64; ++k) {
            float4 wv = *((const float4*)&ws[k][c0]);
            float xv[4];
#pragma unroll
            for (int j = 0; j < 4; ++j) xv[j] = xs[n0 + j][kbase + k];
#pragma unroll
            for (int j = 0; j < 4; ++j) {
                acc[j][0] += xv[j] * wv.x;
                acc[j][1] += xv[j] * wv.y;
                acc[j][2] += xv[j] * wv.z;
                acc[j][3] += xv[j] * wv.w;
            }
        }
    }

#pragma unroll
    for (int j = 0; j < 4; ++j) {
        int node = nodeBase + n0 + j;
        if (node < n) {
            float s = dinv[node];
            ushort4 o;
            o.x = __half_as_ushort(__float2half_rn(acc[j][0] * s));
            o.y = __half_as_ushort(__float2half_rn(acc[j][1] * s));
            o.z = __half_as_ushort(__float2half_rn(acc[j][2] * s));
            o.w = __half_as_ushort(__float2half_rn(acc[j][3] * s));
            ((ushort4*)hs)[node * 16 + cg] = o;
        }
    }
}

// 16 B of one hs row: 8 fp16 channels.
struct h8 { __half2 a, b, c, d; };

// One wave per node, transposed gather: lane (g = lane>>3, s = lane&7)
// loads 16 B (channels s*8..s*8+7) of edge j+g. One dwordx4 instruction
// = 8 edges = 8 lines in flight per vmem queue slot.
__global__ __launch_bounds__(256) void k_agg1(const __half* __restrict__ hs,
                                              const int* __restrict__ offset,
                                              const int2* __restrict__ csr,
                                              const float* __restrict__ dinv,
                                              const float* __restrict__ b1,
                                              const float* __restrict__ W2,
                                              float* __restrict__ h2s, int n) {
    int wid  = (int)((blockIdx.x * blockDim.x + threadIdx.x) >> 6);
    int lane = threadIdx.x & 63;
    if (wid >= n) return;
    int off0 = offset[wid], off1 = offset[wid + 1];
    int g = lane >> 3, s = lane & 7;
    const h8* H = (const h8*)hs;     // H[node*8 + s] = channels [s*8, s*8+8)

    float acc[8] = {0.f, 0.f, 0.f, 0.f, 0.f, 0.f, 0.f, 0.f};

    // self term: only group 0 adds it (summed once by the cross-group reduce)
    {
        h8 v = H[(size_t)wid * 8 + s];
        if (g == 0) {
            float2 f;
            f = __half22float2(v.a); acc[0] += f.x; acc[1] += f.y;
            f = __half22float2(v.b); acc[2] += f.x; acc[3] += f.y;
            f = __half22float2(v.c); acc[4] += f.x; acc[5] += f.y;
            f = __half22float2(v.d); acc[6] += f.x; acc[7] += f.y;
        }
    }

    int j = off0;
    for (; j + 16 <= off1; j += 16) {
        int2 eA = csr[j + g];
        int2 eB = csr[j + 8 + g];
        h8 vA = H[(size_t)eA.x * 8 + s];
        h8 vB = H[(size_t)eB.x * 8 + s];
        float wA = __int_as_float(eA.y), wB = __int_as_float(eB.y);
        float2 f;
        f = __half22float2(vA.a); acc[0] += wA * f.x; acc[1] += wA * f.y;
        f = __half22float2(vA.b); acc[2] += wA * f.x; acc[3] += wA * f.y;
        f = __half22float2(vA.c); acc[4] += wA * f.x; acc[5] += wA * f.y;
        f = __half22float2(vA.d); acc[6] += wA * f.x; acc[7] += wA * f.y;
        f = __half22float2(vB.a); acc[0] += wB * f.x; acc[1] += wB * f.y;
        f = __half22float2(vB.b); acc[2] += wB * f.x; acc[3] += wB * f.y;
        f = __half22float2(vB.c); acc[4] += wB * f.x; acc[5] += wB * f.y;
        f = __half22float2(vB.d); acc[6] += wB * f.x; acc[7] += wB * f.y;
    }
    for (; j < off1; j += 8) {
        int idx = j + g;
        bool ok = idx < off1;
        int2 e = csr[ok ? idx : off1 - 1];
        float w = ok ? __int_as_float(e.y) : 0.f;
        h8 v = H[(size_t)e.x * 8 + s];
        float2 f;
        f = __half22float2(v.a); acc[0] += w * f.x; acc[1] += w * f.y;
        f = __half22float2(v.b); acc[2] += w * f.x; acc[3] += w * f.y;
        f = __half22float2(v.c); acc[4] += w * f.x; acc[5] += w * f.y;
        f = __half22float2(v.d); acc[6] += w * f.x; acc[7] += w * f.y;
    }

    // reduce partial channel sums across the 8 groups (lanes with same s)
#pragma unroll
    for (int k = 0; k < 8; ++k) {
        float t = acc[k];
        t += __shfl_xor(t, 8);
        t += __shfl_xor(t, 16);
        t += __shfl_xor(t, 32);
        acc[k] = t;
    }

    float di = dinv[wid];
    float4 bA = ((const float4*)b1)[s * 2], bB = ((const float4*)b1)[s * 2 + 1];
    float4 wA = ((const float4*)W2)[s * 2], wB = ((const float4*)W2)[s * 2 + 1];
    float p = 0.f;
    p += fmaxf(di * acc[0] + bA.x, 0.f) * wA.x;
    p += fmaxf(di * acc[1] + bA.y, 0.f) * wA.y;
    p += fmaxf(di * acc[2] + bA.z, 0.f) * wA.z;
    p += fmaxf(di * acc[3] + bA.w, 0.f) * wA.w;
    p += fmaxf(di * acc[4] + bB.x, 0.f) * wB.x;
    p += fmaxf(di * acc[5] + bB.y, 0.f) * wB.y;
    p += fmaxf(di * acc[6] + bB.z, 0.f) * wB.z;
    p += fmaxf(di * acc[7] + bB.w, 0.f) * wB.w;
    // reduce across s (all groups hold identical values now)
    p += __shfl_xor(p, 1);
    p += __shfl_xor(p, 2);
    p += __shfl_xor(p, 4);
    if (lane == 0) h2s[wid] = di * p;
}

// One wave per node; out[i] = di*(sum_j ew_j*h2s[r_j] + h2s[i]) + b2.
__global__ __launch_bounds__(256) void k_agg2(const float* __restrict__ h2s,
                                              const int* __restrict__ offset,
                                              const int2* __restrict__ csr,
                                              const float* __restrict__ dinv,
                                              const float* __restrict__ b2,
                                              float* __restrict__ out, int n) {
    int wid = __builtin_amdgcn_readfirstlane((int)((blockIdx.x * blockDim.x + threadIdx.x) >> 6));
    int lane = threadIdx.x & 63;
    if (wid >= n) return;
    int off0 = __builtin_amdgcn_readfirstlane(offset[wid]);
    int off1 = __builtin_amdgcn_readfirstlane(offset[wid + 1]);
    float di = dinv[wid];
    float p = 0.f;
    for (int e = off0 + lane; e < off1; e += 64) {
        int2 ed = csr[e];
        p += __int_as_float(ed.y) * h2s[ed.x];
    }
#pragma unroll
    for (int s = 32; s > 0; s >>= 1) p += __shfl_xor(p, s);
    if (lane == 0) out[wid] = di * (p + h2s[wid]) + b2[0];
}

extern "C" void kernel_launch(void* const* d_in, const int* in_sizes, int n_in,
                              void* d_out, int out_size, void* d_ws, size_t ws_size,
                              hipStream_t stream) {
    const float* x  = (const float*)d_in[0];
    const int*   ei = (const int*)  d_in[1];
    const float* ea = (const float*)d_in[2];
    const float* W1 = (const float*)d_in[3];
    const float* b1 = (const float*)d_in[4];
    const float* W2 = (const float*)d_in[5];
    const float* b2 = (const float*)d_in[6];
    float* out = (float*)d_out;

    const int N  = in_sizes[0] / 128;   // 100000 (must be <= 131072)
    const int E  = in_sizes[2];         // 3200000
    const int E4 = E / 4;
    const int nbl  = (E4 + 1023) / 1024;        // partition chunks (<=1024)
    const int nbkt = (N + BSIZE - 1) / BSIZE;   // active buckets (196)

    char* p = (char*)d_ws;
    auto alloc = [&](size_t bytes) -> void* {
        void* r = (void*)p;
        p += (bytes + 255) & ~(size_t)255;
        return r;
    };
    int*    hist   = (int*)   alloc((size_t)nbl * NBUCKET * 4);
    int*    histS  = (int*)   alloc((size_t)NBUCKET * nbl * 4);
    int*    tot    = (int*)   alloc((size_t)NBUCKET * 4);
    int*    base   = (int*)   alloc((size_t)(NBUCKET + 1) * 4);
    int2*   binned = (int2*)  alloc((size_t)E * 8);
    int2*   csr    = (int2*)  alloc((size_t)E * 8);
    int*    offset = (int*)   alloc((size_t)(N + 1) * 4);
    float*  dinv   = (float*) alloc((size_t)N * 4);
    __half* hs     = (__half*)alloc((size_t)N * 64 * 2);
    float*  h2s    = (float*) alloc((size_t)N * 4);

    const int nb_gemm = (N + 63) / 64;
    const int nb_wave = (N * 64 + 255) / 256;   // one 64-wide wave per node

    k_hist<<<nbl, 256, 0, stream>>>(ei + E, hist, E4);
    k_scan_bucket<<<NBUCKET, 256, 0, stream>>>(hist, histS, tot, nbl);
    k_scan_tot<<<1, 256, 0, stream>>>(tot, base);
    k_scatter<<<nbl, 256, 0, stream>>>(ei, ea, histS, base, binned, E, E4, nbl);
    k_finalize<<<nbkt, 256, 0, stream>>>(binned, base, csr, offset, dinv, N, E);
    k_gemm<<<nb_gemm, 256, 0, stream>>>(x, W1, dinv, hs, N);
    k_agg1<<<nb_wave, 256, 0, stream>>>(hs, offset, csr, dinv, b1, W2, h2s, N);
    k_agg2<<<nb_wave, 256, 0, stream>>>(h2s, offset, csr, dinv, b2, out, N);
}